// Round 7
// baseline (523.836 us; speedup 1.0000x reference)
//
#include <hip/hip_runtime.h>
#include <hip/hip_bf16.h>

typedef __bf16 bf16_t;
typedef __bf16 bf16x8 __attribute__((ext_vector_type(8)));
typedef float f32x4 __attribute__((ext_vector_type(4)));

#define QSCALE 0.1803368801111396f   /* 0.125 * log2(e) */
#define MLOG2E 1.4426950408889634f

__device__ __forceinline__ f32x4 mfma16(bf16x8 a, bf16x8 b, f32x4 c) {
  return __builtin_amdgcn_mfma_f32_16x16x32_bf16(a, b, c, 0, 0, 0);
}

#define GLDS16(gsrc, ldst)                                                     \
  __builtin_amdgcn_global_load_lds(                                            \
      (const __attribute__((address_space(1))) void*)(gsrc),                   \
      (__attribute__((address_space(3))) void*)(ldst), 16, 0, 0)

__device__ __forceinline__ unsigned short bhalf(float f) {
  return __builtin_bit_cast(unsigned short, (bf16_t)f);
}

// ---------------------------------------------------------------------------
// prep: rel f32(4095,64) -> bf16(4096,64); mbias = (1-mask)*-1e9*log2e
// ---------------------------------------------------------------------------
__global__ void prep_kernel(const float* __restrict__ rel,
                            const float* __restrict__ mask,
                            bf16_t* __restrict__ relb,
                            float* __restrict__ mbias) {
  int idx = blockIdx.x * 256 + threadIdx.x;
  if (idx < 4096 * 64) {
    int row = idx >> 6;
    int col = idx & 63;
    int sr = row > 4094 ? 4094 : row;
    relb[idx] = (bf16_t)rel[sr * 64 + col];
  } else {
    int j = idx - 4096 * 64;
    if (j < 4096) mbias[j] = (1.0f - mask[j]) * -1e9f * MLOG2E;
  }
}

// ---------------------------------------------------------------------------
// Fused projection GEMM: z=0 -> qb scaled by 0.125*log2e, (b,h,t,p) layout.
// z=1 -> kb (b,h,t,p).  z=2 -> vb TRANSPOSED (b,h,p,t).
// ---------------------------------------------------------------------------
__global__ __launch_bounds__(256) void proj_gemm_kernel(
    const float* __restrict__ Q, const float* __restrict__ K,
    const float* __restrict__ V, const float* __restrict__ WQ,
    const float* __restrict__ WK, const float* __restrict__ WV,
    bf16_t* __restrict__ qb, bf16_t* __restrict__ kb,
    bf16_t* __restrict__ vb) {
  const int z = blockIdx.z;
  const float* A = z == 0 ? Q : (z == 1 ? K : V);
  const float* W = z == 0 ? WQ : (z == 1 ? WK : WV);
  bf16_t* out = z == 0 ? qb : (z == 1 ? kb : vb);
  const float scale = z == 0 ? QSCALE : 1.0f;

  __shared__ bf16_t As[128][72];
  __shared__ bf16_t Bs[128][72];
  const int tid = threadIdx.x;
  const int lane = tid & 63;
  const int wid = tid >> 6;
  const int wm = wid >> 1, wn = wid & 1;
  const int row0 = blockIdx.x * 128;
  const int col0 = blockIdx.y * 128;
  const int lr = lane & 15;
  const int lk = (lane >> 4) * 8;

  f32x4 acc[4][4];
#pragma unroll
  for (int m = 0; m < 4; m++)
#pragma unroll
    for (int n = 0; n < 4; n++) acc[m][n] = {0.f, 0.f, 0.f, 0.f};

  for (int kt = 0; kt < 1024; kt += 64) {
#pragma unroll
    for (int i = 0; i < 4; i++) {
      int c = tid + i * 256;
      int row = c >> 3;
      int k8 = (c & 7) * 8;
      const float* src = A + (size_t)(row0 + row) * 1024 + kt + k8;
      bf16_t* dst = &As[row][k8];
#pragma unroll
      for (int j = 0; j < 8; j++) dst[j] = (bf16_t)src[j];
    }
#pragma unroll
    for (int i = 0; i < 4; i++) {
      int c = tid + i * 256;
      int col = c & 127;
      int k8 = (c >> 7) * 8;
      int gcol = col0 + col;
      int h = gcol >> 6, p = gcol & 63;
      const float* src = W + (size_t)h * 65536 + (size_t)(kt + k8) * 64 + p;
      bf16_t* dst = &Bs[col][k8];
#pragma unroll
      for (int j = 0; j < 8; j++) dst[j] = (bf16_t)src[j * 64];
    }
    __syncthreads();
#pragma unroll
    for (int kk = 0; kk < 2; kk++) {
      bf16x8 af[4], bfr[4];
#pragma unroll
      for (int m = 0; m < 4; m++)
        af[m] = *(const bf16x8*)&As[wm * 64 + m * 16 + lr][kk * 32 + lk];
#pragma unroll
      for (int n = 0; n < 4; n++)
        bfr[n] = *(const bf16x8*)&Bs[wn * 64 + n * 16 + lr][kk * 32 + lk];
#pragma unroll
      for (int m = 0; m < 4; m++)
#pragma unroll
        for (int n = 0; n < 4; n++)
          acc[m][n] = mfma16(af[m], bfr[n], acc[m][n]);
    }
    __syncthreads();
  }
  const int rb = (lane >> 4) * 4;
#pragma unroll
  for (int m = 0; m < 4; m++) {
#pragma unroll
    for (int n = 0; n < 4; n++) {
      int col = col0 + wn * 64 + n * 16 + lr;
      int h = col >> 6, p = col & 63;
      int row_base = row0 + wm * 64 + m * 16 + rb;
      int b = row_base >> 11, t0 = row_base & 2047;
      if (z == 2) {
        unsigned u0 = ((unsigned)bhalf(acc[m][n][1]) << 16) | bhalf(acc[m][n][0]);
        unsigned u1 = ((unsigned)bhalf(acc[m][n][3]) << 16) | bhalf(acc[m][n][2]);
        uint2 u = {u0, u1};
        *(uint2*)&out[(((size_t)(b * 16 + h) * 64 + p) * 2048) + t0] = u;
      } else {
#pragma unroll
        for (int r = 0; r < 4; r++) {
          out[(((size_t)(b * 16 + h) * 2048 + t0 + r) * 64) + p] =
              (bf16_t)(acc[m][n][r] * scale);
        }
      }
    }
  }
}

// ---------------------------------------------------------------------------
// Dense output GEMM: out = ctx(bf16) @ W(f32) + bias
// ---------------------------------------------------------------------------
__global__ __launch_bounds__(256) void dense_gemm_kernel(
    const bf16_t* __restrict__ A, const float* __restrict__ W,
    const float* __restrict__ bias, float* __restrict__ out) {
  __shared__ bf16_t As[128][72];
  __shared__ bf16_t Bs[128][72];
  const int tid = threadIdx.x;
  const int lane = tid & 63;
  const int wid = tid >> 6;
  const int wm = wid >> 1, wn = wid & 1;
  const int row0 = blockIdx.x * 128;
  const int col0 = blockIdx.y * 128;
  const int lr = lane & 15;
  const int lk = (lane >> 4) * 8;

  f32x4 acc[4][4];
#pragma unroll
  for (int m = 0; m < 4; m++)
#pragma unroll
    for (int n = 0; n < 4; n++) acc[m][n] = {0.f, 0.f, 0.f, 0.f};

  for (int kt = 0; kt < 1024; kt += 64) {
#pragma unroll
    for (int i = 0; i < 4; i++) {
      int c = tid + i * 256;
      int row = c >> 3;
      int k8 = (c & 7) * 8;
      *(uint4*)&As[row][k8] =
          *(const uint4*)(A + (size_t)(row0 + row) * 1024 + kt + k8);
    }
#pragma unroll
    for (int i = 0; i < 4; i++) {
      int c = tid + i * 256;
      int col = c & 127;
      int k8 = (c >> 7) * 8;
      const float* src = W + (size_t)(kt + k8) * 1024 + col0 + col;
      bf16_t* dst = &Bs[col][k8];
#pragma unroll
      for (int j = 0; j < 8; j++) dst[j] = (bf16_t)src[j * 1024];
    }
    __syncthreads();
#pragma unroll
    for (int kk = 0; kk < 2; kk++) {
      bf16x8 af[4], bfr[4];
#pragma unroll
      for (int m = 0; m < 4; m++)
        af[m] = *(const bf16x8*)&As[wm * 64 + m * 16 + lr][kk * 32 + lk];
#pragma unroll
      for (int n = 0; n < 4; n++)
        bfr[n] = *(const bf16x8*)&Bs[wn * 64 + n * 16 + lr][kk * 32 + lk];
#pragma unroll
      for (int m = 0; m < 4; m++)
#pragma unroll
        for (int n = 0; n < 4; n++)
          acc[m][n] = mfma16(af[m], bfr[n], acc[m][n]);
    }
    __syncthreads();
  }
  const int rb = (lane >> 4) * 4;
#pragma unroll
  for (int m = 0; m < 4; m++) {
#pragma unroll
    for (int n = 0; n < 4; n++) {
      int col = col0 + wn * 64 + n * 16 + lr;
      float bv = bias[col];
#pragma unroll
      for (int r = 0; r < 4; r++) {
        int row = row0 + wm * 64 + m * 16 + rb + r;
        out[(size_t)row * 1024 + col] = acc[m][n][r] + bv;
      }
    }
  }
}

// ---------------------------------------------------------------------------
// Flash attention, swapped-operand.  DS-pipe diet:
//   K,V fragments go global->VGPR on the vmem pipe (L1/L2-resident via XCD
//   remap); only R is LDS-staged (ring of 3, prefetched 2 jts ahead).
//   K regs reloaded right after QK consumes them (cover = softmax+B0);
//   V regs loaded at phase A (cover = QK+softmax).  ONE barrier per jt.
// ---------------------------------------------------------------------------
__global__ __launch_bounds__(256, 3) void attn_kernel(
    const bf16_t* __restrict__ qg, const bf16_t* __restrict__ kg,
    const bf16_t* __restrict__ vt, const bf16_t* __restrict__ relb,
    const float* __restrict__ mbias, bf16_t* __restrict__ ctx) {
  __shared__ bf16_t Rr[3][64 * 64];    // 24 KB ring (64-row chunks)
  __shared__ unsigned EL[4][16 * 43];  // 10.75 KB per-wave bias band
  __shared__ bf16_t PL[4][16 * 68];    //  8.5 KB per-wave P^T

  const int tid = threadIdx.x;
  const int lane = tid & 63;
  const int w = tid >> 6;

  // XCD-bijective remap (1024 = 8 x 128)
  const int id = blockIdx.x + 32 * (blockIdx.y + 16 * blockIdx.z);
  const int id2 = (id & 7) * 128 + (id >> 3);
  const int it = id2 & 31;
  const int bh = id2 >> 5;
  const int h = bh & 15;
  const int b = bh >> 4;
  const int i0 = it * 64;

  const size_t base = ((size_t)bh) * 2048 * 64;
  const int lr = lane & 15;
  const int g = lane >> 4;
  const int lk = g * 8;
  const int nbase = 3 - w;     // wave's rel-band start frag
  const int srow = lane >> 3;  // staging row-within-chunk
  const int t16 = lane & 7;    // staging 16B slot
  const int swz = (lr & 7) << 3;

  const bf16_t* rgb = relb + (size_t)(1984 - i0) * 64;
  // fragment bases (16B slices of row-major global arrays)
  const bf16_t* kp0 = kg + base + (size_t)lr * 64 + lk;    // +j0*64+n*1024+kk*32
  const bf16_t* vp0 = vt + base + (size_t)lr * 2048 + lk;  // +j0+n*32768+kk*32

  bf16x8 aq[2];
  {
    const bf16_t* src = qg + base + (size_t)(i0 + w * 16 + lr) * 64 + lk;
    aq[0] = *(const bf16x8*)(src);
    aq[1] = *(const bf16x8*)(src + 32);
  }

  float m = -INFINITY, l = 0.f;
  f32x4 o[4];
#pragma unroll
  for (int n = 0; n < 4; n++) o[n] = {0.f, 0.f, 0.f, 0.f};

  const float* mb_base = mbias + (size_t)b * 2048;

  bf16x8 kreg[8], vreg[8];

  // ---- prologue: K[0] into regs; stage R chunks 0,1
#pragma unroll
  for (int kk = 0; kk < 2; kk++)
#pragma unroll
    for (int n = 0; n < 4; n++)
      kreg[kk * 4 + n] = *(const bf16x8*)(kp0 + n * 1024 + kk * 32);
#pragma unroll
  for (int c = 0; c < 2; c++) {
#pragma unroll
    for (int i = 0; i < 2; i++) {
      int chunk = i * 4 + w;
      int row = chunk * 8 + srow;
      GLDS16(rgb + (size_t)(c * 64 + row) * 64 + ((t16 ^ (row & 7)) * 8),
             Rr[c] + chunk * 512 + lane * 8);
    }
  }
  __syncthreads();

  for (int jt = 0; jt < 32; jt++) {
    const int j0 = jt * 64;

    // ---- phase A: V[jt] into regs (vmem; cover = QK + softmax)
    {
      const bf16_t* vp = vp0 + j0;
#pragma unroll
      for (int kk = 0; kk < 2; kk++)
#pragma unroll
        for (int n = 0; n < 4; n++)
          vreg[kk * 4 + n] = *(const bf16x8*)(vp + n * 32768 + kk * 32);
    }
    // ---- stage R[jt+2] chunk into ring (GLDS; cover = full phase)
    if (jt < 30) {
      bf16_t* rd = Rr[(jt + 2) % 3];
      const bf16_t* rs = rgb + (size_t)(jt + 2) * 64 * 64;
#pragma unroll
      for (int i = 0; i < 2; i++) {
        int chunk = i * 4 + w;
        int row = chunk * 8 + srow;
        GLDS16(rs + row * 64 + ((t16 ^ (row & 7)) * 8),
               rd + chunk * 512 + lane * 8);
      }
    }

    // ---- S^T = K q^T (regs) ; Er^T = R q^T (LDS ring)
    f32x4 sacc[4], er[5];
#pragma unroll
    for (int n = 0; n < 4; n++) sacc[n] = {0.f, 0.f, 0.f, 0.f};
#pragma unroll
    for (int n = 0; n < 5; n++) er[n] = {0.f, 0.f, 0.f, 0.f};
    const int slot0 = jt % 3, slot1 = (jt + 1) % 3;
    __builtin_amdgcn_s_setprio(1);
#pragma unroll
    for (int kk = 0; kk < 2; kk++) {
      int cbs = (kk * 32 + lk) ^ swz;
#pragma unroll
      for (int n = 0; n < 4; n++)
        sacc[n] = mfma16(kreg[kk * 4 + n], aq[kk], sacc[n]);
#pragma unroll
      for (int n2 = 0; n2 < 5; n2++) {
        int fr = nbase + n2;  // frag row index 0..7
        const bf16_t* rc = (fr >> 2) ? Rr[slot1] : Rr[slot0];
        bf16x8 ar = *(const bf16x8*)&rc[(((fr & 3) * 16) + lr) * 64 + cbs];
        er[n2] = mfma16(ar, aq[kk], er[n2]);
      }
    }
    __builtin_amdgcn_s_setprio(0);

    // ---- reload kreg with K[jt+1] (vmem; cover = softmax + barrier absorb)
    if (jt < 31) {
      const bf16_t* kp = kp0 + (size_t)(j0 + 64) * 64;
#pragma unroll
      for (int kk = 0; kk < 2; kk++)
#pragma unroll
        for (int n = 0; n < 4; n++)
          kreg[kk * 4 + n] = *(const bf16x8*)(kp + n * 1024 + kk * 32);
    }

    // ---- spill rel band (per-wave, packed u32, stride 43)
#pragma unroll
    for (int n2 = 0; n2 < 5; n2++) {
      EL[w][lr * 43 + n2 * 8 + g * 2 + 0] =
          ((unsigned)bhalf(er[n2][1]) << 16) | bhalf(er[n2][0]);
      EL[w][lr * 43 + n2 * 8 + g * 2 + 1] =
          ((unsigned)bhalf(er[n2][3]) << 16) | bhalf(er[n2][2]);
    }

    // ---- energies: s[key] = sacc + bias[key-lr+15] + mbias[key]
    float s[4][4];
#pragma unroll
    for (int n = 0; n < 4; n++) {
      f32x4 mbv = *(const f32x4*)&mb_base[j0 + n * 16 + g * 4];
#pragma unroll
      for (int r = 0; r < 4; r++) {
        int key = n * 16 + g * 4 + r;
        int idx = key - lr + 15;  // in [0,78]
        unsigned d = EL[w][lr * 43 + (idx >> 1)];
        float bias = __builtin_bit_cast(float, (d >> ((idx & 1) << 4)) << 16);
        s[n][r] = sacc[n][r] + bias + mbv[r];
      }
    }
    // ---- in-lane softmax + 2-shfl cross-group reduce, defer-max rescale
    float a0 = fmaxf(fmaxf(s[0][0], s[0][1]), fmaxf(s[0][2], s[0][3]));
    float a1 = fmaxf(fmaxf(s[1][0], s[1][1]), fmaxf(s[1][2], s[1][3]));
    float a2 = fmaxf(fmaxf(s[2][0], s[2][1]), fmaxf(s[2][2], s[2][3]));
    float a3 = fmaxf(fmaxf(s[3][0], s[3][1]), fmaxf(s[3][2], s[3][3]));
    float pm = fmaxf(fmaxf(a0, a1), fmaxf(a2, a3));
    pm = fmaxf(pm, __shfl_xor(pm, 16, 64));
    pm = fmaxf(pm, __shfl_xor(pm, 32, 64));
    if (!__all(pm - m <= 8.f)) {
      float mnew = fmaxf(m, pm);
      float fac = exp2f(m - mnew);
      m = mnew;
      l *= fac;
#pragma unroll
      for (int n = 0; n < 4; n++) {
        o[n][0] *= fac; o[n][1] *= fac; o[n][2] *= fac; o[n][3] *= fac;
      }
    }
    float ps = 0.f;
#pragma unroll
    for (int n = 0; n < 4; n++) {
      float e0 = exp2f(s[n][0] - m);
      float e1 = exp2f(s[n][1] - m);
      float e2 = exp2f(s[n][2] - m);
      float e3 = exp2f(s[n][3] - m);
      s[n][0] = e0; s[n][1] = e1; s[n][2] = e2; s[n][3] = e3;
      ps += (e0 + e1) + (e2 + e3);
    }
    ps += __shfl_xor(ps, 16, 64);
    ps += __shfl_xor(ps, 32, 64);
    l += ps;
    // ---- P^T -> per-wave LDS (stride 68, packed uint2)
#pragma unroll
    for (int n = 0; n < 4; n++) {
      unsigned u0 = ((unsigned)bhalf(s[n][1]) << 16) | bhalf(s[n][0]);
      unsigned u1 = ((unsigned)bhalf(s[n][3]) << 16) | bhalf(s[n][2]);
      uint2 u = {u0, u1};
      *(uint2*)&PL[w][lr * 68 + n * 16 + g * 4] = u;
    }

    __syncthreads();  // drains vmem (vreg/kreg/R-stage); orders ring WAR

    // ---- ctx^T += V^T P  (A from vreg, B from PL)
    __builtin_amdgcn_s_setprio(1);
#pragma unroll
    for (int kk = 0; kk < 2; kk++) {
      bf16x8 bp = *(const bf16x8*)&PL[w][lr * 68 + kk * 32 + lk];
#pragma unroll
      for (int n = 0; n < 4; n++) o[n] = mfma16(vreg[kk * 4 + n], bp, o[n]);
    }
    __builtin_amdgcn_s_setprio(0);
  }

  // ---- write ctx (bt, h*64+p): o rows are p, col (=lr) is query
  float inv = 1.0f / l;
  size_t bt = (size_t)b * 2048 + i0 + w * 16 + lr;
#pragma unroll
  for (int n = 0; n < 4; n++) {
    unsigned u0 = ((unsigned)bhalf(o[n][1] * inv) << 16) | bhalf(o[n][0] * inv);
    unsigned u1 = ((unsigned)bhalf(o[n][3] * inv) << 16) | bhalf(o[n][2] * inv);
    uint2 u = {u0, u1};
    *(uint2*)&ctx[bt * 1024 + h * 64 + n * 16 + g * 4] = u;
  }
}

// ---------------------------------------------------------------------------
extern "C" void kernel_launch(void* const* d_in, const int* in_sizes, int n_in,
                              void* d_out, int out_size, void* d_ws,
                              size_t ws_size, hipStream_t stream) {
  (void)in_sizes; (void)n_in; (void)out_size; (void)ws_size;
  const float* Q    = (const float*)d_in[0];
  const float* K    = (const float*)d_in[1];
  const float* V    = (const float*)d_in[2];
  const float* mask = (const float*)d_in[3];
  const float* WQ   = (const float*)d_in[4];
  const float* WK   = (const float*)d_in[5];
  const float* WV   = (const float*)d_in[6];
  const float* rel  = (const float*)d_in[7];
  const float* dW   = (const float*)d_in[8];
  const float* db   = (const float*)d_in[9];
  float* out = (float*)d_out;

  const size_t NQKV = (size_t)2 * 16 * 2048 * 64;
  bf16_t* qb   = (bf16_t*)d_ws;
  bf16_t* kb   = qb + NQKV;
  bf16_t* vb   = kb + NQKV;   // holds V^T (b,h,p,t)
  bf16_t* ctxb = vb + NQKV;
  bf16_t* relb = ctxb + NQKV;                  // 4096*64 bf16
  float*  mbias = (float*)(relb + 4096 * 64);  // 4096 f32

  dim3 blk(256);
  prep_kernel<<<dim3((4096 * 64 + 4096) / 256), blk, 0, stream>>>(rel, mask,
                                                                  relb, mbias);
  proj_gemm_kernel<<<dim3(32, 8, 3), blk, 0, stream>>>(Q, K, V, WQ, WK, WV, qb,
                                                       kb, vb);
  attn_kernel<<<dim3(32, 16, 2), blk, 0, stream>>>(qb, kb, vb, relb, mbias,
                                                   ctxb);
  dense_gemm_kernel<<<dim3(32, 8), blk, 0, stream>>>(ctxb, dW, db, out);
}

// Round 8
// 216.140 us; speedup vs baseline: 2.4236x; 2.4236x over previous
//
#include <hip/hip_runtime.h>
#include <hip/hip_bf16.h>

typedef __bf16 bf16_t;
typedef __bf16 bf16x8 __attribute__((ext_vector_type(8)));
typedef float f32x4 __attribute__((ext_vector_type(4)));

#define QSCALE 0.1803368801111396f   /* 0.125 * log2(e) */
#define MLOG2E 1.4426950408889634f

__device__ __forceinline__ f32x4 mfma16(bf16x8 a, bf16x8 b, f32x4 c) {
  return __builtin_amdgcn_mfma_f32_16x16x32_bf16(a, b, c, 0, 0, 0);
}

#define GLDS16(gsrc, ldst)                                                     \
  __builtin_amdgcn_global_load_lds(                                            \
      (const __attribute__((address_space(1))) void*)(gsrc),                   \
      (__attribute__((address_space(3))) void*)(ldst), 16, 0, 0)

__device__ __forceinline__ unsigned short bhalf(float f) {
  return __builtin_bit_cast(unsigned short, (bf16_t)f);
}

// ---------------------------------------------------------------------------
// prep: rel f32(4095,64) -> bf16(4096,64); mbias = (1-mask)*-1e9*log2e
// ---------------------------------------------------------------------------
__global__ void prep_kernel(const float* __restrict__ rel,
                            const float* __restrict__ mask,
                            bf16_t* __restrict__ relb,
                            float* __restrict__ mbias) {
  int idx = blockIdx.x * 256 + threadIdx.x;
  if (idx < 4096 * 64) {
    int row = idx >> 6;
    int col = idx & 63;
    int sr = row > 4094 ? 4094 : row;
    relb[idx] = (bf16_t)rel[sr * 64 + col];
  } else {
    int j = idx - 4096 * 64;
    if (j < 4096) mbias[j] = (1.0f - mask[j]) * -1e9f * MLOG2E;
  }
}

// ---------------------------------------------------------------------------
// Fused projection GEMM: z=0 -> qb scaled by 0.125*log2e, (b,h,t,p) layout.
// z=1 -> kb (b,h,t,p).  z=2 -> vb TRANSPOSED (b,h,p,t).
// ---------------------------------------------------------------------------
__global__ __launch_bounds__(256) void proj_gemm_kernel(
    const float* __restrict__ Q, const float* __restrict__ K,
    const float* __restrict__ V, const float* __restrict__ WQ,
    const float* __restrict__ WK, const float* __restrict__ WV,
    bf16_t* __restrict__ qb, bf16_t* __restrict__ kb,
    bf16_t* __restrict__ vb) {
  const int z = blockIdx.z;
  const float* A = z == 0 ? Q : (z == 1 ? K : V);
  const float* W = z == 0 ? WQ : (z == 1 ? WK : WV);
  bf16_t* out = z == 0 ? qb : (z == 1 ? kb : vb);
  const float scale = z == 0 ? QSCALE : 1.0f;

  __shared__ bf16_t As[128][72];
  __shared__ bf16_t Bs[128][72];
  const int tid = threadIdx.x;
  const int lane = tid & 63;
  const int wid = tid >> 6;
  const int wm = wid >> 1, wn = wid & 1;
  const int row0 = blockIdx.x * 128;
  const int col0 = blockIdx.y * 128;
  const int lr = lane & 15;
  const int lk = (lane >> 4) * 8;

  f32x4 acc[4][4];
#pragma unroll
  for (int m = 0; m < 4; m++)
#pragma unroll
    for (int n = 0; n < 4; n++) acc[m][n] = {0.f, 0.f, 0.f, 0.f};

  for (int kt = 0; kt < 1024; kt += 64) {
#pragma unroll
    for (int i = 0; i < 4; i++) {
      int c = tid + i * 256;
      int row = c >> 3;
      int k8 = (c & 7) * 8;
      const float* src = A + (size_t)(row0 + row) * 1024 + kt + k8;
      bf16_t* dst = &As[row][k8];
#pragma unroll
      for (int j = 0; j < 8; j++) dst[j] = (bf16_t)src[j];
    }
#pragma unroll
    for (int i = 0; i < 4; i++) {
      int c = tid + i * 256;
      int col = c & 127;
      int k8 = (c >> 7) * 8;
      int gcol = col0 + col;
      int h = gcol >> 6, p = gcol & 63;
      const float* src = W + (size_t)h * 65536 + (size_t)(kt + k8) * 64 + p;
      bf16_t* dst = &Bs[col][k8];
#pragma unroll
      for (int j = 0; j < 8; j++) dst[j] = (bf16_t)src[j * 64];
    }
    __syncthreads();
#pragma unroll
    for (int kk = 0; kk < 2; kk++) {
      bf16x8 af[4], bfr[4];
#pragma unroll
      for (int m = 0; m < 4; m++)
        af[m] = *(const bf16x8*)&As[wm * 64 + m * 16 + lr][kk * 32 + lk];
#pragma unroll
      for (int n = 0; n < 4; n++)
        bfr[n] = *(const bf16x8*)&Bs[wn * 64 + n * 16 + lr][kk * 32 + lk];
#pragma unroll
      for (int m = 0; m < 4; m++)
#pragma unroll
        for (int n = 0; n < 4; n++)
          acc[m][n] = mfma16(af[m], bfr[n], acc[m][n]);
    }
    __syncthreads();
  }
  const int rb = (lane >> 4) * 4;
#pragma unroll
  for (int m = 0; m < 4; m++) {
#pragma unroll
    for (int n = 0; n < 4; n++) {
      int col = col0 + wn * 64 + n * 16 + lr;
      int h = col >> 6, p = col & 63;
      int row_base = row0 + wm * 64 + m * 16 + rb;
      int b = row_base >> 11, t0 = row_base & 2047;
      if (z == 2) {
        unsigned u0 = ((unsigned)bhalf(acc[m][n][1]) << 16) | bhalf(acc[m][n][0]);
        unsigned u1 = ((unsigned)bhalf(acc[m][n][3]) << 16) | bhalf(acc[m][n][2]);
        uint2 u = {u0, u1};
        *(uint2*)&out[(((size_t)(b * 16 + h) * 64 + p) * 2048) + t0] = u;
      } else {
#pragma unroll
        for (int r = 0; r < 4; r++) {
          out[(((size_t)(b * 16 + h) * 2048 + t0 + r) * 64) + p] =
              (bf16_t)(acc[m][n][r] * scale);
        }
      }
    }
  }
}

// ---------------------------------------------------------------------------
// Dense output GEMM: out = ctx(bf16) @ W(f32) + bias
// ---------------------------------------------------------------------------
__global__ __launch_bounds__(256) void dense_gemm_kernel(
    const bf16_t* __restrict__ A, const float* __restrict__ W,
    const float* __restrict__ bias, float* __restrict__ out) {
  __shared__ bf16_t As[128][72];
  __shared__ bf16_t Bs[128][72];
  const int tid = threadIdx.x;
  const int lane = tid & 63;
  const int wid = tid >> 6;
  const int wm = wid >> 1, wn = wid & 1;
  const int row0 = blockIdx.x * 128;
  const int col0 = blockIdx.y * 128;
  const int lr = lane & 15;
  const int lk = (lane >> 4) * 8;

  f32x4 acc[4][4];
#pragma unroll
  for (int m = 0; m < 4; m++)
#pragma unroll
    for (int n = 0; n < 4; n++) acc[m][n] = {0.f, 0.f, 0.f, 0.f};

  for (int kt = 0; kt < 1024; kt += 64) {
#pragma unroll
    for (int i = 0; i < 4; i++) {
      int c = tid + i * 256;
      int row = c >> 3;
      int k8 = (c & 7) * 8;
      *(uint4*)&As[row][k8] =
          *(const uint4*)(A + (size_t)(row0 + row) * 1024 + kt + k8);
    }
#pragma unroll
    for (int i = 0; i < 4; i++) {
      int c = tid + i * 256;
      int col = c & 127;
      int k8 = (c >> 7) * 8;
      const float* src = W + (size_t)(kt + k8) * 1024 + col0 + col;
      bf16_t* dst = &Bs[col][k8];
#pragma unroll
      for (int j = 0; j < 8; j++) dst[j] = (bf16_t)src[j * 1024];
    }
    __syncthreads();
#pragma unroll
    for (int kk = 0; kk < 2; kk++) {
      bf16x8 af[4], bfr[4];
#pragma unroll
      for (int m = 0; m < 4; m++)
        af[m] = *(const bf16x8*)&As[wm * 64 + m * 16 + lr][kk * 32 + lk];
#pragma unroll
      for (int n = 0; n < 4; n++)
        bfr[n] = *(const bf16x8*)&Bs[wn * 64 + n * 16 + lr][kk * 32 + lk];
#pragma unroll
      for (int m = 0; m < 4; m++)
#pragma unroll
        for (int n = 0; n < 4; n++)
          acc[m][n] = mfma16(af[m], bfr[n], acc[m][n]);
    }
    __syncthreads();
  }
  const int rb = (lane >> 4) * 4;
#pragma unroll
  for (int m = 0; m < 4; m++) {
#pragma unroll
    for (int n = 0; n < 4; n++) {
      int col = col0 + wn * 64 + n * 16 + lr;
      float bv = bias[col];
#pragma unroll
      for (int r = 0; r < 4; r++) {
        int row = row0 + wm * 64 + m * 16 + rb + r;
        out[(size_t)row * 1024 + col] = acc[m][n][r] + bv;
      }
    }
  }
}

// ---------------------------------------------------------------------------
// Flash attention, swapped-operand, QBLK=128: each wave owns TWO 16-query
// groups; K/V/R fragment reads are issued once and feed both groups' MFMAs
// (operand-reuse halves DS traffic per query).  R5 staging skeleton:
// K double-buffered, R ring-of-4 64-row chunks (staged 3 ahead), V single
// buffer, 2 barriers/jt.  P frags for both groups pulled to regs pre-barrier.
// ---------------------------------------------------------------------------
__global__ __launch_bounds__(256, 2) void attn_kernel(
    const bf16_t* __restrict__ qg, const bf16_t* __restrict__ kg,
    const bf16_t* __restrict__ vt, const bf16_t* __restrict__ relb,
    const float* __restrict__ mbias, bf16_t* __restrict__ ctx) {
  __shared__ bf16_t Kb[2][64 * 64];    // 16 KB
  __shared__ bf16_t Vb[64 * 64];       //  8 KB
  __shared__ bf16_t Rr[4][64 * 64];    // 32 KB ring (64-row chunks)
  __shared__ unsigned EL[4][16 * 41];  // 10.25 KB per-wave bias band
  __shared__ bf16_t PL[4][16 * 72];    //  9 KB per-wave P^T

  const int tid = threadIdx.x;
  const int lane = tid & 63;
  const int w = tid >> 6;

  // XCD-bijective remap (512 = 8 x 64): XCD x owns 4 bh's x 16 it's
  const int id = blockIdx.x;
  const int id2 = (id & 7) * 64 + (id >> 3);
  const int it = id2 & 15;
  const int bh = id2 >> 4;
  const int h = bh & 15;
  const int b = bh >> 4;
  const int i0 = it * 128;

  const size_t base = ((size_t)bh) * 2048 * 64;
  const int lr = lane & 15;
  const int g = lane >> 4;
  const int lk = g * 8;
  const int srow = lane >> 3;  // staging row-within-chunk
  const int t16 = lane & 7;    // staging 16B slot
  const int swz = (lr & 7) << 3;

  const bf16_t* kgb = kg + base;
  const bf16_t* vgb = vt + base;
  const bf16_t* rgb = relb + (size_t)(1920 - i0) * 64;  // window base (jt=0)

  // Q fragments: two groups (queries i0 + w*32 + gq*16 + lr)
  bf16x8 aq[2][2];
#pragma unroll
  for (int gq = 0; gq < 2; gq++) {
    const bf16_t* src =
        qg + base + (size_t)(i0 + w * 32 + gq * 16 + lr) * 64 + lk;
    aq[gq][0] = *(const bf16x8*)(src);
    aq[gq][1] = *(const bf16x8*)(src + 32);
  }

  float m0 = -INFINITY, l0 = 0.f, m1 = -INFINITY, l1 = 0.f;
  f32x4 o0[4], o1[4];
#pragma unroll
  for (int n = 0; n < 4; n++) {
    o0[n] = {0.f, 0.f, 0.f, 0.f};
    o1[n] = {0.f, 0.f, 0.f, 0.f};
  }

  const float* mb_base = mbias + (size_t)b * 2048;

  // ---- prologue: K[0] -> Kb[0]; R chunks 0,1,2 -> slots 0,1,2
#pragma unroll
  for (int i = 0; i < 2; i++) {
    int chunk = i * 4 + w;
    int row = chunk * 8 + srow;
    GLDS16(kgb + row * 64 + ((t16 ^ (row & 7)) * 8),
           Kb[0] + chunk * 512 + lane * 8);
  }
#pragma unroll
  for (int c = 0; c < 3; c++) {
#pragma unroll
    for (int i = 0; i < 2; i++) {
      int chunk = i * 4 + w;
      int row = chunk * 8 + srow;
      GLDS16(rgb + (size_t)(c * 64 + row) * 64 + ((t16 ^ (row & 7)) * 8),
             Rr[c] + chunk * 512 + lane * 8);
    }
  }
  __syncthreads();

  for (int jt = 0; jt < 32; jt++) {
    const int j0 = jt * 64;

    // ---- phase A staging (drains at B0): V[jt], K[jt+1], R chunk jt+3
#pragma unroll
    for (int i = 0; i < 2; i++) {
      int chunk = i * 4 + w;
      int p = chunk * 8 + srow;
      GLDS16(vgb + j0 + (size_t)p * 2048 + ((t16 ^ (p & 7)) * 8),
             Vb + chunk * 512 + lane * 8);
    }
    if (jt < 31) {
      const bf16_t* kn = kgb + (size_t)(j0 + 64) * 64;
      bf16_t* kd = Kb[(jt + 1) & 1];
#pragma unroll
      for (int i = 0; i < 2; i++) {
        int chunk = i * 4 + w;
        int row = chunk * 8 + srow;
        GLDS16(kn + row * 64 + ((t16 ^ (row & 7)) * 8),
               kd + chunk * 512 + lane * 8);
      }
      const bf16_t* rs = rgb + (size_t)(jt + 3) * 64 * 64;
      bf16_t* rd = Rr[(jt + 3) & 3];
#pragma unroll
      for (int i = 0; i < 2; i++) {
        int chunk = i * 4 + w;
        int row = chunk * 8 + srow;
        GLDS16(rs + row * 64 + ((t16 ^ (row & 7)) * 8),
               rd + chunk * 512 + lane * 8);
      }
    }

    // ---- QK + rel band, both groups share every operand read
    f32x4 sacc0[4], sacc1[4], er0[5], er1[5];
#pragma unroll
    for (int n = 0; n < 4; n++) {
      sacc0[n] = {0.f, 0.f, 0.f, 0.f};
      sacc1[n] = {0.f, 0.f, 0.f, 0.f};
    }
#pragma unroll
    for (int n = 0; n < 5; n++) {
      er0[n] = {0.f, 0.f, 0.f, 0.f};
      er1[n] = {0.f, 0.f, 0.f, 0.f};
    }
    const bf16_t* kcur = Kb[jt & 1];
    __builtin_amdgcn_s_setprio(1);
#pragma unroll
    for (int kk = 0; kk < 2; kk++) {
      int cbs = (kk * 32 + lk) ^ swz;
#pragma unroll
      for (int n = 0; n < 4; n++) {
        bf16x8 ak = *(const bf16x8*)&kcur[(n * 16 + lr) * 64 + cbs];
        sacc0[n] = mfma16(ak, aq[0][kk], sacc0[n]);
        sacc1[n] = mfma16(ak, aq[1][kk], sacc1[n]);
      }
#pragma unroll
      for (int fi = 0; fi < 6; fi++) {
        int f = 6 - 2 * w + fi;  // frag row index in window (0..11)
        const bf16_t* rc = Rr[(jt + (f >> 2)) & 3];
        bf16x8 ar = *(const bf16x8*)&rc[((f & 3) * 16 + lr) * 64 + cbs];
        if (fi >= 1) er0[fi - 1] = mfma16(ar, aq[0][kk], er0[fi - 1]);
        if (fi <= 4) er1[fi] = mfma16(ar, aq[1][kk], er1[fi]);
      }
    }
    __builtin_amdgcn_s_setprio(0);

    // ---- softmax both groups (sequential, EL reused; per-wave in-order DS)
    bf16x8 bp0[2], bp1[2];
#pragma unroll
    for (int gq = 0; gq < 2; gq++) {
      f32x4* sacc = gq ? sacc1 : sacc0;
      f32x4* er = gq ? er1 : er0;
      float m = gq ? m1 : m0;
      float l = gq ? l1 : l0;
      f32x4* o = gq ? o1 : o0;
      // spill rel band
#pragma unroll
      for (int n2 = 0; n2 < 5; n2++) {
        EL[w][lr * 41 + n2 * 8 + g * 2 + 0] =
            ((unsigned)bhalf(er[n2][1]) << 16) | bhalf(er[n2][0]);
        EL[w][lr * 41 + n2 * 8 + g * 2 + 1] =
            ((unsigned)bhalf(er[n2][3]) << 16) | bhalf(er[n2][2]);
      }
      // energies
      float s[4][4];
#pragma unroll
      for (int n = 0; n < 4; n++) {
        f32x4 mbv = *(const f32x4*)&mb_base[j0 + n * 16 + g * 4];
#pragma unroll
        for (int r = 0; r < 4; r++) {
          int key = n * 16 + g * 4 + r;
          int idx = key - lr + 15;  // in [0,78]
          unsigned d = EL[w][lr * 41 + (idx >> 1)];
          float bias = __builtin_bit_cast(float, (d >> ((idx & 1) << 4)) << 16);
          s[n][r] = sacc[n][r] + bias + mbv[r];
        }
      }
      // in-lane max + 2-shfl reduce, defer-max
      float a0 = fmaxf(fmaxf(s[0][0], s[0][1]), fmaxf(s[0][2], s[0][3]));
      float a1 = fmaxf(fmaxf(s[1][0], s[1][1]), fmaxf(s[1][2], s[1][3]));
      float a2 = fmaxf(fmaxf(s[2][0], s[2][1]), fmaxf(s[2][2], s[2][3]));
      float a3 = fmaxf(fmaxf(s[3][0], s[3][1]), fmaxf(s[3][2], s[3][3]));
      float pmx = fmaxf(fmaxf(a0, a1), fmaxf(a2, a3));
      pmx = fmaxf(pmx, __shfl_xor(pmx, 16, 64));
      pmx = fmaxf(pmx, __shfl_xor(pmx, 32, 64));
      if (!__all(pmx - m <= 8.f)) {
        float mnew = fmaxf(m, pmx);
        float fac = exp2f(m - mnew);
        m = mnew;
        l *= fac;
#pragma unroll
        for (int n = 0; n < 4; n++) {
          o[n][0] *= fac; o[n][1] *= fac; o[n][2] *= fac; o[n][3] *= fac;
        }
      }
      float ps = 0.f;
#pragma unroll
      for (int n = 0; n < 4; n++) {
        float e0 = exp2f(s[n][0] - m);
        float e1 = exp2f(s[n][1] - m);
        float e2 = exp2f(s[n][2] - m);
        float e3 = exp2f(s[n][3] - m);
        s[n][0] = e0; s[n][1] = e1; s[n][2] = e2; s[n][3] = e3;
        ps += (e0 + e1) + (e2 + e3);
      }
      ps += __shfl_xor(ps, 16, 64);
      ps += __shfl_xor(ps, 32, 64);
      l += ps;
      if (gq) { m1 = m; l1 = l; } else { m0 = m; l0 = l; }
      // P^T -> per-wave LDS (stride 72, packed uint2) and straight back to
      // B-operand regs (per-wave in-order DS; done before the barrier)
#pragma unroll
      for (int n = 0; n < 4; n++) {
        unsigned u0 = ((unsigned)bhalf(s[n][1]) << 16) | bhalf(s[n][0]);
        unsigned u1 = ((unsigned)bhalf(s[n][3]) << 16) | bhalf(s[n][2]);
        uint2 u = {u0, u1};
        *(uint2*)&PL[w][lr * 72 + n * 16 + g * 4] = u;
      }
      if (gq) {
        bp1[0] = *(const bf16x8*)&PL[w][lr * 72 + lk];
        bp1[1] = *(const bf16x8*)&PL[w][lr * 72 + 32 + lk];
      } else {
        bp0[0] = *(const bf16x8*)&PL[w][lr * 72 + lk];
        bp0[1] = *(const bf16x8*)&PL[w][lr * 72 + 32 + lk];
      }
    }

    __syncthreads();  // B0: drains staging (Vb/K-next/R-next ready)

    // ---- ctx^T += V^T P  (shared av reads feed both groups)
    __builtin_amdgcn_s_setprio(1);
#pragma unroll
    for (int kk = 0; kk < 2; kk++) {
      int cbs = (kk * 32 + lk) ^ swz;
#pragma unroll
      for (int n = 0; n < 4; n++) {
        bf16x8 av = *(const bf16x8*)&Vb[(n * 16 + lr) * 64 + cbs];
        o0[n] = mfma16(av, bp0[kk], o0[n]);
        o1[n] = mfma16(av, bp1[kk], o1[n]);
      }
    }
    __builtin_amdgcn_s_setprio(0);

    __syncthreads();  // B1: PV's Vb reads done before next jt's V stage
  }

  // ---- write ctx (bt, h*64+p): o rows are p, col (=lr) is query
#pragma unroll
  for (int gq = 0; gq < 2; gq++) {
    f32x4* o = gq ? o1 : o0;
    float inv = 1.0f / (gq ? l1 : l0);
    size_t bt = (size_t)b * 2048 + i0 + w * 32 + gq * 16 + lr;
#pragma unroll
    for (int n = 0; n < 4; n++) {
      unsigned u0 = ((unsigned)bhalf(o[n][1] * inv) << 16) | bhalf(o[n][0] * inv);
      unsigned u1 = ((unsigned)bhalf(o[n][3] * inv) << 16) | bhalf(o[n][2] * inv);
      uint2 u = {u0, u1};
      *(uint2*)&ctx[bt * 1024 + h * 64 + n * 16 + g * 4] = u;
    }
  }
}

// ---------------------------------------------------------------------------
extern "C" void kernel_launch(void* const* d_in, const int* in_sizes, int n_in,
                              void* d_out, int out_size, void* d_ws,
                              size_t ws_size, hipStream_t stream) {
  (void)in_sizes; (void)n_in; (void)out_size; (void)ws_size;
  const float* Q    = (const float*)d_in[0];
  const float* K    = (const float*)d_in[1];
  const float* V    = (const float*)d_in[2];
  const float* mask = (const float*)d_in[3];
  const float* WQ   = (const float*)d_in[4];
  const float* WK   = (const float*)d_in[5];
  const float* WV   = (const float*)d_in[6];
  const float* rel  = (const float*)d_in[7];
  const float* dW   = (const float*)d_in[8];
  const float* db   = (const float*)d_in[9];
  float* out = (float*)d_out;

  const size_t NQKV = (size_t)2 * 16 * 2048 * 64;
  bf16_t* qb   = (bf16_t*)d_ws;
  bf16_t* kb   = qb + NQKV;
  bf16_t* vb   = kb + NQKV;   // holds V^T (b,h,p,t)
  bf16_t* ctxb = vb + NQKV;
  bf16_t* relb = ctxb + NQKV;                  // 4096*64 bf16
  float*  mbias = (float*)(relb + 4096 * 64);  // 4096 f32

  dim3 blk(256);
  prep_kernel<<<dim3((4096 * 64 + 4096) / 256), blk, 0, stream>>>(rel, mask,
                                                                  relb, mbias);
  proj_gemm_kernel<<<dim3(32, 8, 3), blk, 0, stream>>>(Q, K, V, WQ, WK, WV, qb,
                                                       kb, vb);
  attn_kernel<<<dim3(512), blk, 0, stream>>>(qb, kb, vb, relb, mbias, ctxb);
  dense_gemm_kernel<<<dim3(32, 8), blk, 0, stream>>>(ctxb, dW, db, out);
}